// Round 1
// baseline (2490.567 us; speedup 1.0000x reference)
//
#include <hip/hip_runtime.h>
#include <hip/hip_bf16.h>
#include <math.h>

// Problem constants
#define N_ROWS 512      // B*S = 4*128
#define D_IN   512      // embedded_input feature dim
#define E_EMB  256      // emb_table dim
#define H_DIM  512      // hidden
#define G_DIM  2048     // 4*H
#define V_DIM  32000    // vocab
#define IN_LD  1280     // [ x(512) | emb(256) | h(512) ]
#define K_STEPS 4
#define OOV_ID 1

// GEMM tiling
#define BM 64
#define BN 64
#define BK 16
#define PAD 4           // LDS pad: keeps 16B alignment for b128 reads, breaks conflicts
#define KC_CHUNK 1280   // split-K chunk for emb GEMM (32000 / 25)

// ---------------------------------------------------------------------------
// init: inpbuf[:,0:512]=x, inpbuf[:,512:768]=emb_table[OOV], inpbuf[:,768:1280]=0 (h0)
//       c = 0
__global__ __launch_bounds__(256) void k_init(const float* __restrict__ x,
                                              const float* __restrict__ emb_table,
                                              float* __restrict__ inpbuf,
                                              float* __restrict__ c) {
    int idx = blockIdx.x * blockDim.x + threadIdx.x;
    int stride = gridDim.x * blockDim.x;
    const int total = N_ROWS * IN_LD;
    for (int i = idx; i < total; i += stride) {
        int n = i / IN_LD;
        int col = i - n * IN_LD;
        float v;
        if (col < D_IN)              v = x[(size_t)n * D_IN + col];
        else if (col < D_IN + E_EMB) v = emb_table[(size_t)OOV_ID * E_EMB + (col - D_IN)];
        else                         v = 0.0f;
        inpbuf[i] = v;
    }
    for (int i = idx; i < N_ROWS * H_DIM; i += stride) c[i] = 0.0f;
}

// ---------------------------------------------------------------------------
// gates = inpbuf(512x1280) @ [W_ih|W_hh]^T (2048x1280) + b_ih + b_hh
__global__ __launch_bounds__(256) void k_gates(const float* __restrict__ inpbuf,
                                               const float* __restrict__ W_ih,
                                               const float* __restrict__ W_hh,
                                               const float* __restrict__ b_ih,
                                               const float* __restrict__ b_hh,
                                               float* __restrict__ gates) {
    __shared__ float As[BK][BM + PAD];
    __shared__ float Bs[BK][BN + PAD];
    const int tid = threadIdx.x;
    const int tx = tid & 15, ty = tid >> 4;
    const int n0 = blockIdx.x * BN;   // over G_DIM
    const int m0 = blockIdx.y * BM;   // over N_ROWS
    float acc[4][4] = {};
    for (int k0 = 0; k0 < IN_LD; k0 += BK) {
#pragma unroll
        for (int r = 0; r < 4; ++r) {
            int idx = tid + r * 256;
            int k = idx & 15, m = idx >> 4;
            As[k][m] = inpbuf[(size_t)(m0 + m) * IN_LD + k0 + k];
        }
#pragma unroll
        for (int r = 0; r < 4; ++r) {
            int idx = tid + r * 256;
            int k = idx & 15, g = idx >> 4;
            int kk = k0 + k;
            float v = (kk < D_IN + E_EMB)
                          ? W_ih[(size_t)(n0 + g) * (D_IN + E_EMB) + kk]
                          : W_hh[(size_t)(n0 + g) * H_DIM + (kk - (D_IN + E_EMB))];
            Bs[k][g] = v;
        }
        __syncthreads();
#pragma unroll
        for (int kk = 0; kk < BK; ++kk) {
            float a[4], b[4];
#pragma unroll
            for (int i = 0; i < 4; ++i) a[i] = As[kk][ty * 4 + i];
#pragma unroll
            for (int j = 0; j < 4; ++j) b[j] = Bs[kk][tx * 4 + j];
#pragma unroll
            for (int i = 0; i < 4; ++i)
#pragma unroll
                for (int j = 0; j < 4; ++j) acc[i][j] += a[i] * b[j];
        }
        __syncthreads();
    }
#pragma unroll
    for (int i = 0; i < 4; ++i) {
        int m = m0 + ty * 4 + i;
#pragma unroll
        for (int j = 0; j < 4; ++j) {
            int g = n0 + tx * 4 + j;
            gates[(size_t)m * G_DIM + g] = acc[i][j] + b_ih[g] + b_hh[g];
        }
    }
}

// ---------------------------------------------------------------------------
// LSTM cell: torch gate order i,f,g,o. Writes c (fp32) and h into inpbuf[:,768:1280]
__global__ __launch_bounds__(256) void k_lstm(const float* __restrict__ gates,
                                              float* __restrict__ c,
                                              float* __restrict__ inpbuf) {
    int idx = blockIdx.x * blockDim.x + threadIdx.x;
    if (idx >= N_ROWS * H_DIM) return;
    int n = idx / H_DIM, j = idx - n * H_DIM;
    const float* gr = gates + (size_t)n * G_DIM;
    float gi = gr[j], gf = gr[j + H_DIM], gg = gr[j + 2 * H_DIM], go = gr[j + 3 * H_DIM];
    float i_ = 1.0f / (1.0f + expf(-gi));
    float f_ = 1.0f / (1.0f + expf(-gf));
    float g_ = tanhf(gg);
    float o_ = 1.0f / (1.0f + expf(-go));
    float cn = f_ * c[idx] + i_ * g_;
    float hn = o_ * tanhf(cn);
    c[idx] = cn;
    inpbuf[(size_t)n * IN_LD + (D_IN + E_EMB) + j] = hn;
}

// ---------------------------------------------------------------------------
// logits = h(512x512) @ W_out^T (32000x512) + b_out  -> written straight into out
__global__ __launch_bounds__(256) void k_logits(const float* __restrict__ inpbuf,
                                                const float* __restrict__ W_out,
                                                const float* __restrict__ b_out,
                                                float* __restrict__ out, int step) {
    __shared__ float As[BK][BM + PAD];
    __shared__ float Bs[BK][BN + PAD];
    const int tid = threadIdx.x;
    const int tx = tid & 15, ty = tid >> 4;
    const int n0 = blockIdx.x * BN;   // over V_DIM (500 tiles)
    const int m0 = blockIdx.y * BM;   // over N_ROWS
    float acc[4][4] = {};
    for (int k0 = 0; k0 < H_DIM; k0 += BK) {
#pragma unroll
        for (int r = 0; r < 4; ++r) {
            int idx = tid + r * 256;
            int k = idx & 15, m = idx >> 4;
            As[k][m] = inpbuf[(size_t)(m0 + m) * IN_LD + (D_IN + E_EMB) + k0 + k];
        }
#pragma unroll
        for (int r = 0; r < 4; ++r) {
            int idx = tid + r * 256;
            int k = idx & 15, g = idx >> 4;
            Bs[k][g] = W_out[(size_t)(n0 + g) * H_DIM + k0 + k];
        }
        __syncthreads();
#pragma unroll
        for (int kk = 0; kk < BK; ++kk) {
            float a[4], b[4];
#pragma unroll
            for (int i = 0; i < 4; ++i) a[i] = As[kk][ty * 4 + i];
#pragma unroll
            for (int j = 0; j < 4; ++j) b[j] = Bs[kk][tx * 4 + j];
#pragma unroll
            for (int i = 0; i < 4; ++i)
#pragma unroll
                for (int j = 0; j < 4; ++j) acc[i][j] += a[i] * b[j];
        }
        __syncthreads();
    }
#pragma unroll
    for (int i = 0; i < 4; ++i) {
        int m = m0 + ty * 4 + i;
        float* orow = out + ((size_t)m * K_STEPS + step) * V_DIM;
#pragma unroll
        for (int j = 0; j < 4; ++j) {
            int v = n0 + tx * 4 + j;
            orow[v] = acc[i][j] + b_out[v];
        }
    }
}

// ---------------------------------------------------------------------------
// in-place log-softmax over each row of this step's logits; also emits
// last_probs (bf16) and zeroes the emb accumulation slice for the next step.
__global__ __launch_bounds__(256) void k_softmax(float* __restrict__ out,
                                                 __hip_bfloat16* __restrict__ last,
                                                 float* __restrict__ inpbuf, int step) {
    const int n = blockIdx.x;
    float* row = out + ((size_t)n * K_STEPS + step) * V_DIM;
    const int tid = threadIdx.x;
    const int lane = tid & 63, wid = tid >> 6;
    __shared__ float red[4];

    // ---- max ----
    float m = -1e30f;
    for (int v = tid; v < V_DIM; v += 256) m = fmaxf(m, row[v]);
#pragma unroll
    for (int off = 32; off > 0; off >>= 1) m = fmaxf(m, __shfl_down(m, off));
    if (lane == 0) red[wid] = m;
    __syncthreads();
    m = fmaxf(fmaxf(red[0], red[1]), fmaxf(red[2], red[3]));
    __syncthreads();

    // ---- sum exp ----
    float s = 0.0f;
    for (int v = tid; v < V_DIM; v += 256) s += expf(row[v] - m);
#pragma unroll
    for (int off = 32; off > 0; off >>= 1) s += __shfl_down(s, off);
    if (lane == 0) red[wid] = s;
    __syncthreads();
    s = red[0] + red[1] + red[2] + red[3];
    const float lse = m + logf(s);

    // ---- write logp (in place) + probs bf16 ----
    const bool feed = (step < K_STEPS - 1);
    for (int v = tid; v < V_DIM; v += 256) {
        float lp = row[v] - lse;
        row[v] = lp;
        if (feed) last[(size_t)n * V_DIM + v] = __float2bfloat16(expf(lp));
    }
    // zero emb slice for next step's split-K accumulation
    if (feed) {
        for (int e = tid; e < E_EMB; e += 256)
            inpbuf[(size_t)n * IN_LD + D_IN + e] = 0.0f;
    }
}

// ---------------------------------------------------------------------------
// emb = last(512x32000, bf16) @ emb_table(32000x256), split-K with atomicAdd
// into inpbuf[:,512:768] (pre-zeroed by k_softmax of previous step)
__global__ __launch_bounds__(256) void k_emb(const __hip_bfloat16* __restrict__ last,
                                             const float* __restrict__ emb_table,
                                             float* __restrict__ inpbuf) {
    __shared__ float As[BK][BM + PAD];
    __shared__ float Bs[BK][BN + PAD];
    const int tid = threadIdx.x;
    const int tx = tid & 15, ty = tid >> 4;
    const int e0 = blockIdx.x * BN;        // over E_EMB (4 tiles)
    const int m0 = blockIdx.y * BM;        // over N_ROWS (8 tiles)
    const int kbase = blockIdx.z * KC_CHUNK;
    float acc[4][4] = {};
    for (int k0 = kbase; k0 < kbase + KC_CHUNK; k0 += BK) {
#pragma unroll
        for (int r = 0; r < 4; ++r) {
            int idx = tid + r * 256;
            int k = idx & 15, m = idx >> 4;
            As[k][m] = __bfloat162float(last[(size_t)(m0 + m) * V_DIM + k0 + k]);
        }
#pragma unroll
        for (int r = 0; r < 4; ++r) {
            int idx = tid + r * 256;
            int e = idx & 63, kk = idx >> 6;
            Bs[kk][e] = emb_table[(size_t)(k0 + kk) * E_EMB + e0 + e];
        }
        __syncthreads();
#pragma unroll
        for (int kk = 0; kk < BK; ++kk) {
            float a[4], b[4];
#pragma unroll
            for (int i = 0; i < 4; ++i) a[i] = As[kk][ty * 4 + i];
#pragma unroll
            for (int j = 0; j < 4; ++j) b[j] = Bs[kk][tx * 4 + j];
#pragma unroll
            for (int i = 0; i < 4; ++i)
#pragma unroll
                for (int j = 0; j < 4; ++j) acc[i][j] += a[i] * b[j];
        }
        __syncthreads();
    }
#pragma unroll
    for (int i = 0; i < 4; ++i) {
        int m = m0 + ty * 4 + i;
#pragma unroll
        for (int j = 0; j < 4; ++j) {
            int e = e0 + tx * 4 + j;
            atomicAdd(&inpbuf[(size_t)m * IN_LD + D_IN + e], acc[i][j]);
        }
    }
}

// ---------------------------------------------------------------------------
extern "C" void kernel_launch(void* const* d_in, const int* in_sizes, int n_in,
                              void* d_out, int out_size, void* d_ws, size_t ws_size,
                              hipStream_t stream) {
    (void)in_sizes; (void)n_in; (void)out_size; (void)ws_size;
    const float* x       = (const float*)d_in[0];
    // d_in[1] input_mask: all ones, unused by reference math
    const float* emb_tab = (const float*)d_in[2];
    const float* W_ih    = (const float*)d_in[3];
    const float* b_ih    = (const float*)d_in[4];
    const float* W_hh    = (const float*)d_in[5];
    const float* b_hh    = (const float*)d_in[6];
    const float* W_out   = (const float*)d_in[7];
    const float* b_out   = (const float*)d_in[8];
    float* out = (float*)d_out;

    // workspace layout (≈40.6 MB)
    char* ws = (char*)d_ws;
    float* inpbuf = (float*)ws;                 ws += (size_t)N_ROWS * IN_LD * sizeof(float);
    float* c      = (float*)ws;                 ws += (size_t)N_ROWS * H_DIM * sizeof(float);
    float* gates  = (float*)ws;                 ws += (size_t)N_ROWS * G_DIM * sizeof(float);
    __hip_bfloat16* last = (__hip_bfloat16*)ws; ws += (size_t)N_ROWS * V_DIM * sizeof(__hip_bfloat16);

    k_init<<<1024, 256, 0, stream>>>(x, emb_tab, inpbuf, c);
    for (int t = 0; t < K_STEPS; ++t) {
        if (t > 0) {
            dim3 g(E_EMB / BN, N_ROWS / BM, V_DIM / KC_CHUNK);
            k_emb<<<g, 256, 0, stream>>>(last, emb_tab, inpbuf);
        }
        k_gates<<<dim3(G_DIM / BN, N_ROWS / BM), 256, 0, stream>>>(inpbuf, W_ih, W_hh, b_ih, b_hh, gates);
        k_lstm<<<(N_ROWS * H_DIM + 255) / 256, 256, 0, stream>>>(gates, c, inpbuf);
        k_logits<<<dim3(V_DIM / BN, N_ROWS / BM), 256, 0, stream>>>(inpbuf, W_out, b_out, out, t);
        k_softmax<<<N_ROWS, 256, 0, stream>>>(out, last, inpbuf, t);
    }
}

// Round 2
// 914.769 us; speedup vs baseline: 2.7226x; 2.7226x over previous
//
#include <hip/hip_runtime.h>
#include <hip/hip_bf16.h>
#include <math.h>

// Problem constants
#define N_ROWS 512      // B*S
#define D_IN   512
#define E_EMB  256
#define H_DIM  512
#define G_DIM  2048
#define V_DIM  32000
#define IN_LD  1280     // Abuf row: [ x(512) | emb(256) | h(512) ]
#define K_STEPS 4
#define OOV_ID 1
#define TBK 64
#define EMB_SPLIT 25
#define EMB_CHUNK 1280  // 25*1280 = 32000

typedef __attribute__((ext_vector_type(4))) float f32x4;
typedef __attribute__((ext_vector_type(8))) short bf16x8;

__device__ inline short f2b(float v) {
    __hip_bfloat16 h = __float2bfloat16(v);
    return *reinterpret_cast<short*>(&h);
}

// ---------------------------------------------------------------------------
// MFMA GEMM: C(MxN) = A(MxK,bf16,row-major) @ B(NxK,bf16,row-major)^T [+bias]
// 256 threads = 4 waves in 2x2; wave tile (TBM/2)x(TBN/2); 16x16x32 bf16 MFMA.
// MODE 0: C[m*ldc+n] = acc + bias[n];  MODE 1: atomicAdd(&C[m*ldc+n], acc)
template<int TBM, int TBN, int MODE>
__global__ __launch_bounds__(256) void k_gemm(
    const short* __restrict__ A, int lda,
    const short* __restrict__ B, int ldb,
    const float* __restrict__ bias,
    float* __restrict__ C, size_t ldc, int Kc)
{
    constexpr int WMT = TBM / 2, WNT = TBN / 2;
    constexpr int WM = WMT / 16, WN = WNT / 16;
    constexpr int ALOADS = TBM * TBK / (256 * 8);
    constexpr int BLOADS = TBN * TBK / (256 * 8);
    __shared__ short As[TBM][TBK + 8];
    __shared__ short Bs[TBN][TBK + 8];
    const int tid = threadIdx.x;
    const int lane = tid & 63, wid = tid >> 6;
    const int wr = wid & 1, wc = wid >> 1;
    const int quad = lane >> 4, l16 = lane & 15;
    const int m0 = blockIdx.y * TBM, n0 = blockIdx.x * TBN;
    const int kbase = blockIdx.z * Kc;

    f32x4 acc[WM][WN];
#pragma unroll
    for (int i = 0; i < WM; ++i)
#pragma unroll
        for (int j = 0; j < WN; ++j)
#pragma unroll
            for (int r = 0; r < 4; ++r) acc[i][j][r] = 0.0f;

    for (int kt = 0; kt < Kc; kt += TBK) {
        const int k0 = kbase + kt;
#pragma unroll
        for (int i = 0; i < ALOADS; ++i) {
            int q = tid + i * 256;
            int r = q >> 3, cc = (q & 7) * 8;   // 8 chunks of 8 bf16 per 64-wide row
            *(bf16x8*)&As[r][cc] = *(const bf16x8*)&A[(size_t)(m0 + r) * lda + k0 + cc];
        }
#pragma unroll
        for (int i = 0; i < BLOADS; ++i) {
            int q = tid + i * 256;
            int r = q >> 3, cc = (q & 7) * 8;
            *(bf16x8*)&Bs[r][cc] = *(const bf16x8*)&B[(size_t)(n0 + r) * ldb + k0 + cc];
        }
        __syncthreads();
#pragma unroll
        for (int ks = 0; ks < 2; ++ks) {
            bf16x8 af[WM], bfv[WN];
#pragma unroll
            for (int i = 0; i < WM; ++i)
                af[i] = *(const bf16x8*)&As[wr * WMT + i * 16 + l16][ks * 32 + quad * 8];
#pragma unroll
            for (int j = 0; j < WN; ++j)
                bfv[j] = *(const bf16x8*)&Bs[wc * WNT + j * 16 + l16][ks * 32 + quad * 8];
#pragma unroll
            for (int i = 0; i < WM; ++i)
#pragma unroll
                for (int j = 0; j < WN; ++j)
                    acc[i][j] = __builtin_amdgcn_mfma_f32_16x16x32_bf16(af[i], bfv[j], acc[i][j], 0, 0, 0);
        }
        __syncthreads();
    }
    // epilogue: D row = quad*4+reg, col = lane&15
#pragma unroll
    for (int i = 0; i < WM; ++i) {
#pragma unroll
        for (int j = 0; j < WN; ++j) {
            const int n = n0 + wc * WNT + j * 16 + l16;
            const float bv = (MODE == 0 && bias != nullptr) ? bias[n] : 0.0f;
#pragma unroll
            for (int r = 0; r < 4; ++r) {
                const int m = m0 + wr * WMT + i * 16 + quad * 4 + r;
                if (MODE == 0) C[(size_t)m * ldc + n] = acc[i][j][r] + bv;
                else           atomicAdd(&C[(size_t)m * ldc + n], acc[i][j][r]);
            }
        }
    }
}

// ---------------------------------------------------------------------------
// per-launch prep: bf16 weight packs + Abuf init + c zero
__global__ __launch_bounds__(256) void k_prep(
    const float* __restrict__ x, const float* __restrict__ emb_table,
    const float* __restrict__ W_ih, const float* __restrict__ W_hh,
    const float* __restrict__ b_ih, const float* __restrict__ b_hh,
    const float* __restrict__ W_out,
    short* __restrict__ Abuf, short* __restrict__ Wg, float* __restrict__ bsum,
    short* __restrict__ Wout16, float* __restrict__ c)
{
    const int idx0 = blockIdx.x * 256 + threadIdx.x;
    const int gs = gridDim.x * 256;
    for (int i = idx0; i < V_DIM * H_DIM; i += gs) Wout16[i] = f2b(W_out[i]);
    for (int i = idx0; i < G_DIM * IN_LD; i += gs) {
        int g = i / IN_LD, k = i - g * IN_LD;
        float v = (k < D_IN + E_EMB) ? W_ih[(size_t)g * (D_IN + E_EMB) + k]
                                     : W_hh[(size_t)g * H_DIM + (k - (D_IN + E_EMB))];
        Wg[i] = f2b(v);
    }
    for (int i = idx0; i < G_DIM; i += gs) bsum[i] = b_ih[i] + b_hh[i];
    for (int i = idx0; i < N_ROWS * IN_LD; i += gs) {
        int n = i / IN_LD, col = i - n * IN_LD;
        float v;
        if (col < D_IN)              v = x[(size_t)n * D_IN + col];
        else if (col < D_IN + E_EMB) v = emb_table[(size_t)OOV_ID * E_EMB + (col - D_IN)];
        else                         v = 0.0f;
        Abuf[i] = f2b(v);
    }
    for (int i = idx0; i < N_ROWS * H_DIM; i += gs) c[i] = 0.0f;
}

// ---------------------------------------------------------------------------
// emb_T[e][v] = bf16(emb_table[v][e])  (256 x 32000)
__global__ __launch_bounds__(256) void k_trans(const float* __restrict__ emb,
                                               short* __restrict__ embT)
{
    __shared__ float tile[64][65];
    const int v0 = blockIdx.x * 64, e0 = blockIdx.y * 64;
    const int tid = threadIdx.x;
#pragma unroll
    for (int i = 0; i < 16; ++i) {
        int idx = tid + i * 256;
        int vr = idx >> 6, ec = idx & 63;
        tile[vr][ec] = emb[(size_t)(v0 + vr) * E_EMB + e0 + ec];
    }
    __syncthreads();
#pragma unroll
    for (int i = 0; i < 16; ++i) {
        int idx = tid + i * 256;
        int er = idx >> 6, vc = idx & 63;
        embT[(size_t)(e0 + er) * V_DIM + v0 + vc] = f2b(tile[vc][er]);
    }
}

// ---------------------------------------------------------------------------
// LSTM cell (torch order i,f,g,o): c fp32, h -> bf16 into Abuf[:,768:1280)
__global__ __launch_bounds__(256) void k_lstm(const float* __restrict__ gates,
                                              float* __restrict__ c,
                                              short* __restrict__ Abuf)
{
    int idx = blockIdx.x * blockDim.x + threadIdx.x;
    if (idx >= N_ROWS * H_DIM) return;
    int n = idx / H_DIM, j = idx - n * H_DIM;
    const float* gr = gates + (size_t)n * G_DIM;
    float gi = gr[j], gf = gr[j + H_DIM], gg = gr[j + 2 * H_DIM], go = gr[j + 3 * H_DIM];
    float i_ = 1.0f / (1.0f + expf(-gi));
    float f_ = 1.0f / (1.0f + expf(-gf));
    float g_ = tanhf(gg);
    float o_ = 1.0f / (1.0f + expf(-go));
    float cn = f_ * c[idx] + i_ * g_;
    float hn = o_ * tanhf(cn);
    c[idx] = cn;
    Abuf[(size_t)n * IN_LD + (D_IN + E_EMB) + j] = f2b(hn);
}

// ---------------------------------------------------------------------------
// emb_acc fp32 -> bf16 into Abuf[:,512:768)
__global__ __launch_bounds__(256) void k_cvt_emb(const float* __restrict__ emb_acc,
                                                 short* __restrict__ Abuf)
{
    int idx = blockIdx.x * 256 + threadIdx.x;   // 512*256 total
    int n = idx >> 8, e = idx & 255;
    Abuf[(size_t)n * IN_LD + D_IN + e] = f2b(emb_acc[idx]);
}

// ---------------------------------------------------------------------------
// 2-pass online log-softmax in place; emits bf16 probs; zeroes emb_acc for next step
__global__ __launch_bounds__(256) void k_softmax(float* __restrict__ out,
                                                 short* __restrict__ last,
                                                 float* __restrict__ emb_acc, int step)
{
    const int n = blockIdx.x;
    float* row = out + ((size_t)n * K_STEPS + step) * V_DIM;
    const int tid = threadIdx.x;
    const int lane = tid & 63, wid = tid >> 6;
    __shared__ float redm[4], reds[4];

    float m = -1e30f, s = 0.0f;
    const float4* row4 = (const float4*)row;
    for (int v = tid; v < V_DIM / 4; v += 256) {
        float4 xv = row4[v];
        float mx = fmaxf(fmaxf(xv.x, xv.y), fmaxf(xv.z, xv.w));
        float nm = fmaxf(m, mx);
        s = s * __expf(m - nm) + __expf(xv.x - nm) + __expf(xv.y - nm)
                               + __expf(xv.z - nm) + __expf(xv.w - nm);
        m = nm;
    }
#pragma unroll
    for (int off = 32; off > 0; off >>= 1) {
        float m2 = __shfl_down(m, off), s2 = __shfl_down(s, off);
        float nm = fmaxf(m, m2);
        s = s * __expf(m - nm) + s2 * __expf(m2 - nm);
        m = nm;
    }
    if (lane == 0) { redm[wid] = m; reds[wid] = s; }
    __syncthreads();
    float fm = redm[0], fs = reds[0];
#pragma unroll
    for (int w = 1; w < 4; ++w) {
        float nm = fmaxf(fm, redm[w]);
        fs = fs * __expf(fm - nm) + reds[w] * __expf(redm[w] - nm);
        fm = nm;
    }
    const float lse = fm + __logf(fs);

    const bool feed = (step < K_STEPS - 1);
    float4* row4w = (float4*)row;
    for (int v = tid; v < V_DIM / 4; v += 256) {
        float4 xv = row4[v];
        float lp0 = xv.x - lse, lp1 = xv.y - lse, lp2 = xv.z - lse, lp3 = xv.w - lse;
        row4w[v] = make_float4(lp0, lp1, lp2, lp3);
        if (feed) {
            short4 p;
            p.x = f2b(__expf(lp0)); p.y = f2b(__expf(lp1));
            p.z = f2b(__expf(lp2)); p.w = f2b(__expf(lp3));
            *(short4*)&last[(size_t)n * V_DIM + 4 * v] = p;
        }
    }
    if (feed) {
        for (int e = tid; e < E_EMB; e += 256)
            emb_acc[(size_t)n * E_EMB + e] = 0.0f;
    }
}

// ---------------------------------------------------------------------------
extern "C" void kernel_launch(void* const* d_in, const int* in_sizes, int n_in,
                              void* d_out, int out_size, void* d_ws, size_t ws_size,
                              hipStream_t stream) {
    (void)in_sizes; (void)n_in; (void)out_size; (void)ws_size;
    const float* x       = (const float*)d_in[0];
    const float* emb_tab = (const float*)d_in[2];
    const float* W_ih    = (const float*)d_in[3];
    const float* b_ih    = (const float*)d_in[4];
    const float* W_hh    = (const float*)d_in[5];
    const float* b_hh    = (const float*)d_in[6];
    const float* W_out   = (const float*)d_in[7];
    const float* b_out   = (const float*)d_in[8];
    float* out = (float*)d_out;

    // workspace carve (~94 MB, all 16B-aligned)
    char* ws = (char*)d_ws;
    short* Abuf   = (short*)ws;  ws += (size_t)N_ROWS * IN_LD * sizeof(short);
    float* c      = (float*)ws;  ws += (size_t)N_ROWS * H_DIM * sizeof(float);
    float* gates  = (float*)ws;  ws += (size_t)N_ROWS * G_DIM * sizeof(float);
    short* last   = (short*)ws;  ws += (size_t)N_ROWS * V_DIM * sizeof(short);
    short* Wout16 = (short*)ws;  ws += (size_t)V_DIM * H_DIM * sizeof(short);
    short* Wg     = (short*)ws;  ws += (size_t)G_DIM * IN_LD * sizeof(short);
    float* bsum   = (float*)ws;  ws += (size_t)G_DIM * sizeof(float);
    short* embT   = (short*)ws;  ws += (size_t)E_EMB * V_DIM * sizeof(short);
    float* emb_acc= (float*)ws;  ws += (size_t)N_ROWS * E_EMB * sizeof(float);

    k_prep<<<2048, 256, 0, stream>>>(x, emb_tab, W_ih, W_hh, b_ih, b_hh, W_out,
                                     Abuf, Wg, bsum, Wout16, c);
    k_trans<<<dim3(V_DIM / 64, E_EMB / 64), 256, 0, stream>>>(emb_tab, embT);

    for (int t = 0; t < K_STEPS; ++t) {
        if (t > 0) {
            // emb_acc += last(512x32000) @ embT^T(256x32000)^T, split-K
            k_gemm<128, 128, 1><<<dim3(E_EMB / 128, N_ROWS / 128, EMB_SPLIT), 256, 0, stream>>>(
                last, V_DIM, embT, V_DIM, nullptr, emb_acc, E_EMB, EMB_CHUNK);
            k_cvt_emb<<<N_ROWS * E_EMB / 256, 256, 0, stream>>>(emb_acc, Abuf);
        }
        // gates = Abuf(512x1280) @ Wg(2048x1280)^T + bsum
        k_gemm<64, 64, 0><<<dim3(G_DIM / 64, N_ROWS / 64, 1), 256, 0, stream>>>(
            Abuf, IN_LD, Wg, IN_LD, bsum, gates, G_DIM, IN_LD);
        k_lstm<<<(N_ROWS * H_DIM + 255) / 256, 256, 0, stream>>>(gates, c, Abuf);
        // logits = h(512x512) @ Wout16(32000x512)^T + b_out -> out[:, t, :]
        k_gemm<128, 128, 0><<<dim3(V_DIM / 128, N_ROWS / 128, 1), 256, 0, stream>>>(
            Abuf + (D_IN + E_EMB), IN_LD, Wout16, H_DIM, b_out,
            out + (size_t)t * V_DIM, (size_t)K_STEPS * V_DIM, H_DIM);
        k_softmax<<<N_ROWS, 256, 0, stream>>>(out, last, emb_acc, t);
    }
}

// Round 3
// 811.419 us; speedup vs baseline: 3.0694x; 1.1274x over previous
//
#include <hip/hip_runtime.h>
#include <hip/hip_bf16.h>
#include <math.h>

// Problem constants
#define N_ROWS 512      // B*S
#define D_IN   512
#define E_EMB  256
#define H_DIM  512
#define G_DIM  2048
#define V_DIM  32000
#define IN_LD  1280     // Abuf row: [ x(512) | emb(256) | h(512) ]
#define K_STEPS 4
#define OOV_ID 1
#define TBK 64
#define EMB_SPLIT 25
#define EMB_CHUNK 1280  // 25*1280 = 32000
#define SEGSTRIDE 512   // stats row stride (500 used)

typedef __attribute__((ext_vector_type(4))) float f32x4;
typedef __attribute__((ext_vector_type(8))) short bf16x8;

__device__ inline short f2b(float v) {
    __hip_bfloat16 h = __float2bfloat16(v);
    return *reinterpret_cast<short*>(&h);
}

// async global->LDS, 16B per lane; dest = ldsbase + lane*16 (wave-uniform base)
__device__ inline void gload_lds(const short* g, short* l) {
    __builtin_amdgcn_global_load_lds(
        (const __attribute__((address_space(1))) void*)g,
        (__attribute__((address_space(3))) void*)l, 16, 0, 0);
}

// ---------------------------------------------------------------------------
// MFMA GEMM: C(MxN) = A(MxK,bf16 rm) @ B(NxK,bf16 rm)^T [+bias]
// 256 thr = 4 waves 2x2. global_load_lds staging, XOR-swizzled LDS chunks.
// MODE 0: C = acc + bias[n]   MODE 1: atomicAdd(&C, acc)
// STATS 1: additionally emit per-(row, 64-col segment) (max, sumexp) partials.
template<int TBM, int TBN, int MODE, int STATS>
__global__ __launch_bounds__(256) void k_gemm(
    const short* __restrict__ A, int lda,
    const short* __restrict__ B, int ldb,
    const float* __restrict__ bias,
    float* __restrict__ C, size_t ldc, int Kc,
    float2* __restrict__ stats)
{
    constexpr int WMT = TBM / 2, WNT = TBN / 2;
    constexpr int WM = WMT / 16, WN = WNT / 16;
    __shared__ short As[TBM * 64];
    __shared__ short Bs[TBN * 64];
    const int tid = threadIdx.x;
    const int lane = tid & 63, wid = tid >> 6;
    const int wr = wid & 1, wc = wid >> 1;
    const int quad = lane >> 4, l16 = lane & 15;
    const int m0 = blockIdx.y * TBM, n0 = blockIdx.x * TBN;
    const int kbase = blockIdx.z * Kc;
    // staging lane geometry: 8 rows/instr, 8 chunks of 8 bf16 per row, XOR swizzle
    const int lrow = lane >> 3;
    const int lsw  = ((lane & 7) ^ lrow) * 8;

    f32x4 acc[WM][WN];
#pragma unroll
    for (int i = 0; i < WM; ++i)
#pragma unroll
        for (int j = 0; j < WN; ++j)
#pragma unroll
            for (int r = 0; r < 4; ++r) acc[i][j][r] = 0.0f;

    for (int kt = 0; kt < Kc; kt += TBK) {
        const int k0 = kbase + kt;
#pragma unroll
        for (int ch = wid; ch < TBM / 8; ch += 4)
            gload_lds(&A[(size_t)(m0 + ch * 8 + lrow) * lda + k0 + lsw], &As[ch * 512]);
#pragma unroll
        for (int ch = wid; ch < TBN / 8; ch += 4)
            gload_lds(&B[(size_t)(n0 + ch * 8 + lrow) * ldb + k0 + lsw], &Bs[ch * 512]);
        __syncthreads();
#pragma unroll
        for (int ks = 0; ks < 2; ++ks) {
            bf16x8 af[WM], bfv[WN];
#pragma unroll
            for (int i = 0; i < WM; ++i) {
                int rr = wr * WMT + i * 16 + l16;
                af[i] = *(const bf16x8*)&As[rr * 64 + (((ks * 4 + quad) ^ (l16 & 7)) * 8)];
            }
#pragma unroll
            for (int j = 0; j < WN; ++j) {
                int rr = wc * WNT + j * 16 + l16;
                bfv[j] = *(const bf16x8*)&Bs[rr * 64 + (((ks * 4 + quad) ^ (l16 & 7)) * 8)];
            }
#pragma unroll
            for (int i = 0; i < WM; ++i)
#pragma unroll
                for (int j = 0; j < WN; ++j)
                    acc[i][j] = __builtin_amdgcn_mfma_f32_16x16x32_bf16(af[i], bfv[j], acc[i][j], 0, 0, 0);
        }
        __syncthreads();
    }

    // epilogue. C layout: row = quad*4 + reg, col = l16
    if (MODE == 1) {
#pragma unroll
        for (int i = 0; i < WM; ++i)
#pragma unroll
            for (int j = 0; j < WN; ++j) {
                const int n = n0 + wc * WNT + j * 16 + l16;
#pragma unroll
                for (int r = 0; r < 4; ++r) {
                    const int m = m0 + wr * WMT + i * 16 + quad * 4 + r;
                    atomicAdd(&C[(size_t)m * ldc + n], acc[i][j][r]);
                }
            }
    } else {
        float bv[WN];
#pragma unroll
        for (int j = 0; j < WN; ++j) bv[j] = bias[n0 + wc * WNT + j * 16 + l16];
#pragma unroll
        for (int i = 0; i < WM; ++i) {
            if (!STATS) {
#pragma unroll
                for (int j = 0; j < WN; ++j) {
                    const int n = n0 + wc * WNT + j * 16 + l16;
#pragma unroll
                    for (int r = 0; r < 4; ++r) {
                        const int m = m0 + wr * WMT + i * 16 + quad * 4 + r;
                        C[(size_t)m * ldc + n] = acc[i][j][r] + bv[j];
                    }
                }
            } else {
                float rm[4] = {-1e30f, -1e30f, -1e30f, -1e30f};
                float rs[4] = {0.f, 0.f, 0.f, 0.f};
#pragma unroll
                for (int j = 0; j < WN; ++j)
#pragma unroll
                    for (int r = 0; r < 4; ++r)
                        rm[r] = fmaxf(rm[r], acc[i][j][r] + bv[j]);
#pragma unroll
                for (int j = 0; j < WN; ++j) {
                    const int n = n0 + wc * WNT + j * 16 + l16;
#pragma unroll
                    for (int r = 0; r < 4; ++r) {
                        const int m = m0 + wr * WMT + i * 16 + quad * 4 + r;
                        float z = acc[i][j][r] + bv[j];
                        rs[r] += __expf(z - rm[r]);
                        C[(size_t)m * ldc + n] = z;
                    }
                }
                // merge (max,sum) across the 16 l16-lanes of this quad
#pragma unroll
                for (int mask = 1; mask < 16; mask <<= 1) {
#pragma unroll
                    for (int r = 0; r < 4; ++r) {
                        float om = __shfl_xor(rm[r], mask);
                        float os = __shfl_xor(rs[r], mask);
                        float nm = fmaxf(rm[r], om);
                        rs[r] = rs[r] * __expf(rm[r] - nm) + os * __expf(om - nm);
                        rm[r] = nm;
                    }
                }
                if (l16 == 0) {
                    const int seg = blockIdx.x * 2 + wc;
#pragma unroll
                    for (int r = 0; r < 4; ++r) {
                        const int m = m0 + wr * WMT + i * 16 + quad * 4 + r;
                        stats[(size_t)m * SEGSTRIDE + seg] = make_float2(rm[r], rs[r]);
                    }
                }
            }
        }
    }
}

// ---------------------------------------------------------------------------
// per-launch prep: bf16 weight packs + Abuf init + c zero
__global__ __launch_bounds__(256) void k_prep(
    const float* __restrict__ x, const float* __restrict__ emb_table,
    const float* __restrict__ W_ih, const float* __restrict__ W_hh,
    const float* __restrict__ b_ih, const float* __restrict__ b_hh,
    const float* __restrict__ W_out,
    short* __restrict__ Abuf, short* __restrict__ Wg, float* __restrict__ bsum,
    short* __restrict__ Wout16, float* __restrict__ c)
{
    const int idx0 = blockIdx.x * 256 + threadIdx.x;
    const int gs = gridDim.x * 256;
    const float4* W4 = (const float4*)W_out;
    for (int i = idx0; i < V_DIM * H_DIM / 4; i += gs) {
        float4 v = W4[i];
        short4 o;
        o.x = f2b(v.x); o.y = f2b(v.y); o.z = f2b(v.z); o.w = f2b(v.w);
        ((short4*)Wout16)[i] = o;
    }
    for (int i = idx0; i < G_DIM * IN_LD; i += gs) {
        int g = i / IN_LD, k = i - g * IN_LD;
        float v = (k < D_IN + E_EMB) ? W_ih[(size_t)g * (D_IN + E_EMB) + k]
                                     : W_hh[(size_t)g * H_DIM + (k - (D_IN + E_EMB))];
        Wg[i] = f2b(v);
    }
    for (int i = idx0; i < G_DIM; i += gs) bsum[i] = b_ih[i] + b_hh[i];
    for (int i = idx0; i < N_ROWS * IN_LD; i += gs) {
        int n = i / IN_LD, col = i - n * IN_LD;
        float v;
        if (col < D_IN)              v = x[(size_t)n * D_IN + col];
        else if (col < D_IN + E_EMB) v = emb_table[(size_t)OOV_ID * E_EMB + (col - D_IN)];
        else                         v = 0.0f;
        Abuf[i] = f2b(v);
    }
    for (int i = idx0; i < N_ROWS * H_DIM; i += gs) c[i] = 0.0f;
}

// ---------------------------------------------------------------------------
// emb_T[e][v] = bf16(emb_table[v][e])  (256 x 32000)
__global__ __launch_bounds__(256) void k_trans(const float* __restrict__ emb,
                                               short* __restrict__ embT)
{
    __shared__ float tile[64][65];
    const int v0 = blockIdx.x * 64, e0 = blockIdx.y * 64;
    const int tid = threadIdx.x;
#pragma unroll
    for (int i = 0; i < 16; ++i) {
        int idx = tid + i * 256;
        int vr = idx >> 6, ec = idx & 63;
        tile[vr][ec] = emb[(size_t)(v0 + vr) * E_EMB + e0 + ec];
    }
    __syncthreads();
#pragma unroll
    for (int i = 0; i < 16; ++i) {
        int idx = tid + i * 256;
        int er = idx >> 6, vc = idx & 63;
        embT[(size_t)(e0 + er) * V_DIM + v0 + vc] = f2b(tile[vc][er]);
    }
}

// ---------------------------------------------------------------------------
// LSTM cell (torch order i,f,g,o): c fp32, h -> bf16 into Abuf[:,768:1280)
__global__ __launch_bounds__(256) void k_lstm(const float* __restrict__ gates,
                                              float* __restrict__ c,
                                              short* __restrict__ Abuf)
{
    int idx = blockIdx.x * blockDim.x + threadIdx.x;
    if (idx >= N_ROWS * H_DIM) return;
    int n = idx / H_DIM, j = idx - n * H_DIM;
    const float* gr = gates + (size_t)n * G_DIM;
    float gi = gr[j], gf = gr[j + H_DIM], gg = gr[j + 2 * H_DIM], go = gr[j + 3 * H_DIM];
    float i_ = 1.0f / (1.0f + expf(-gi));
    float f_ = 1.0f / (1.0f + expf(-gf));
    float g_ = tanhf(gg);
    float o_ = 1.0f / (1.0f + expf(-go));
    float cn = f_ * c[idx] + i_ * g_;
    float hn = o_ * tanhf(cn);
    c[idx] = cn;
    Abuf[(size_t)n * IN_LD + (D_IN + E_EMB) + j] = f2b(hn);
}

// ---------------------------------------------------------------------------
// emb_acc fp32 -> bf16 into Abuf[:,512:768)
__global__ __launch_bounds__(256) void k_cvt_emb(const float* __restrict__ emb_acc,
                                                 short* __restrict__ Abuf)
{
    int idx = blockIdx.x * 256 + threadIdx.x;   // 512*256 total
    int n = idx >> 8, e = idx & 255;
    Abuf[(size_t)n * IN_LD + D_IN + e] = f2b(emb_acc[idx]);
}

// ---------------------------------------------------------------------------
// lse from GEMM-emitted segment stats, then single pass: logp in place + bf16 probs
__global__ __launch_bounds__(256) void k_softmax(float* __restrict__ out,
                                                 short* __restrict__ last,
                                                 float* __restrict__ emb_acc,
                                                 const float2* __restrict__ stats,
                                                 int step)
{
    const int n = blockIdx.x;
    float* row = out + ((size_t)n * K_STEPS + step) * V_DIM;
    const int tid = threadIdx.x;
    const int lane = tid & 63, wid = tid >> 6;
    __shared__ float redm[4], reds[4];

    float m = -1e30f, s = 0.0f;
    for (int sg = tid; sg < V_DIM / 64; sg += 256) {
        float2 p = stats[(size_t)n * SEGSTRIDE + sg];
        float nm = fmaxf(m, p.x);
        s = s * __expf(m - nm) + p.y * __expf(p.x - nm);
        m = nm;
    }
#pragma unroll
    for (int off = 32; off > 0; off >>= 1) {
        float m2 = __shfl_down(m, off), s2 = __shfl_down(s, off);
        float nm = fmaxf(m, m2);
        s = s * __expf(m - nm) + s2 * __expf(m2 - nm);
        m = nm;
    }
    if (lane == 0) { redm[wid] = m; reds[wid] = s; }
    __syncthreads();
    float fm = redm[0], fs = reds[0];
#pragma unroll
    for (int w = 1; w < 4; ++w) {
        float nm = fmaxf(fm, redm[w]);
        fs = fs * __expf(fm - nm) + reds[w] * __expf(redm[w] - nm);
        fm = nm;
    }
    const float lse = fm + __logf(fs);

    const bool feed = (step < K_STEPS - 1);
    const float4* row4 = (const float4*)row;
    float4* row4w = (float4*)row;
    for (int v = tid; v < V_DIM / 4; v += 256) {
        float4 xv = row4[v];
        float lp0 = xv.x - lse, lp1 = xv.y - lse, lp2 = xv.z - lse, lp3 = xv.w - lse;
        row4w[v] = make_float4(lp0, lp1, lp2, lp3);
        if (feed) {
            short4 p;
            p.x = f2b(__expf(lp0)); p.y = f2b(__expf(lp1));
            p.z = f2b(__expf(lp2)); p.w = f2b(__expf(lp3));
            *(short4*)&last[(size_t)n * V_DIM + 4 * v] = p;
        }
    }
    if (feed) {
        for (int e = tid; e < E_EMB; e += 256)
            emb_acc[(size_t)n * E_EMB + e] = 0.0f;
    }
}

// ---------------------------------------------------------------------------
extern "C" void kernel_launch(void* const* d_in, const int* in_sizes, int n_in,
                              void* d_out, int out_size, void* d_ws, size_t ws_size,
                              hipStream_t stream) {
    (void)in_sizes; (void)n_in; (void)out_size; (void)ws_size;
    const float* x       = (const float*)d_in[0];
    const float* emb_tab = (const float*)d_in[2];
    const float* W_ih    = (const float*)d_in[3];
    const float* b_ih    = (const float*)d_in[4];
    const float* W_hh    = (const float*)d_in[5];
    const float* b_hh    = (const float*)d_in[6];
    const float* W_out   = (const float*)d_in[7];
    const float* b_out   = (const float*)d_in[8];
    float* out = (float*)d_out;

    // workspace carve (~96 MB, all 16B-aligned)
    char* ws = (char*)d_ws;
    short* Abuf   = (short*)ws;  ws += (size_t)N_ROWS * IN_LD * sizeof(short);
    float* c      = (float*)ws;  ws += (size_t)N_ROWS * H_DIM * sizeof(float);
    float* gates  = (float*)ws;  ws += (size_t)N_ROWS * G_DIM * sizeof(float);
    short* last   = (short*)ws;  ws += (size_t)N_ROWS * V_DIM * sizeof(short);
    short* Wout16 = (short*)ws;  ws += (size_t)V_DIM * H_DIM * sizeof(short);
    short* Wg     = (short*)ws;  ws += (size_t)G_DIM * IN_LD * sizeof(short);
    float* bsum   = (float*)ws;  ws += (size_t)G_DIM * sizeof(float);
    short* embT   = (short*)ws;  ws += (size_t)E_EMB * V_DIM * sizeof(short);
    float* emb_acc= (float*)ws;  ws += (size_t)N_ROWS * E_EMB * sizeof(float);
    float2* stats = (float2*)ws; ws += (size_t)N_ROWS * SEGSTRIDE * sizeof(float2);

    k_prep<<<2048, 256, 0, stream>>>(x, emb_tab, W_ih, W_hh, b_ih, b_hh, W_out,
                                     Abuf, Wg, bsum, Wout16, c);
    k_trans<<<dim3(V_DIM / 64, E_EMB / 64), 256, 0, stream>>>(emb_tab, embT);

    for (int t = 0; t < K_STEPS; ++t) {
        if (t > 0) {
            // emb_acc += last(512x32000) @ embT(256x32000)^T, split-K
            k_gemm<128, 128, 1, 0><<<dim3(E_EMB / 128, N_ROWS / 128, EMB_SPLIT), 256, 0, stream>>>(
                last, V_DIM, embT, V_DIM, nullptr, emb_acc, E_EMB, EMB_CHUNK, nullptr);
            k_cvt_emb<<<N_ROWS * E_EMB / 256, 256, 0, stream>>>(emb_acc, Abuf);
        }
        // gates = Abuf(512x1280) @ Wg(2048x1280)^T + bsum
        k_gemm<64, 64, 0, 0><<<dim3(G_DIM / 64, N_ROWS / 64, 1), 256, 0, stream>>>(
            Abuf, IN_LD, Wg, IN_LD, bsum, gates, G_DIM, IN_LD, nullptr);
        k_lstm<<<(N_ROWS * H_DIM + 255) / 256, 256, 0, stream>>>(gates, c, Abuf);
        // logits = h(512x512) @ Wout16(32000x512)^T + b_out -> out[:, t, :] (+ stats)
        k_gemm<128, 128, 0, 1><<<dim3(V_DIM / 128, N_ROWS / 128, 1), 256, 0, stream>>>(
            Abuf + (D_IN + E_EMB), IN_LD, Wout16, H_DIM, b_out,
            out + (size_t)t * V_DIM, (size_t)K_STEPS * V_DIM, H_DIM, stats);
        k_softmax<<<N_ROWS, 256, 0, stream>>>(out, last, emb_acc, stats, t);
    }
}